// Round 9
// baseline (244.704 us; speedup 1.0000x reference)
//
#include <hip/hip_runtime.h>
#include <hip/hip_bf16.h>

// RoutingLayer: B=128,S=64,N=32, D=128, K=8 capsules x C=16, 3 routing iters.
// fp32 OR bf16 inputs (runtime-detected), MFMA GEMM, fused routing.
// R14 (fuse normalize + iter0 into the epilogue; cut 2 barriers):
//  - R13 was neutral: per-phase LDS op trims are latency-hidden. The kernel
//    is phase-serialization bound (8 barriers, short latency-chained phases,
//    no pipe >41%). Remove phases, not ops.
//  - Key fact: post-GEMM each wave holds ALL 33 rows for its 2 cols in regs
//    (mt0=rows 0-15, mt1=16-31, mt2=row-32 broadcast -> same value in every
//    lane). A capsule's 16 cols = the 16 ml lanes of a quarter-wave.
//  - Epilogue now: relu -> per-row ss via shfl_xor(1,2,4,8) over ml ->
//    write NORMALIZED zn; iter-0 u = 0.125*sum(rows, via xor 16,32) +
//    self_norm, normalized via ml-reduce, q==0 writes uu. normalize and
//    iter0 phases (and their barriers + LDS chains) deleted. 8 -> 6 barriers.
//  - s_setprio(1) around MFMA cluster: independent blocks (attn-like regime).
// Carried: two-kernel dtype dispatch, R12 low-pressure GEMM schedule,
// 8 blocks/CU, v_perm splits, conflict-free lane maps, PPS=40 pass2.

#define NB 32
#define DD 128
#define ZS 132   // zn row stride (floats)
#define PPS 40   // pp row stride (floats) — 160B, 16B-aligned
#define AST 136  // staged A row stride (bf16 units) = 272 B, 16B-aligned

// LDS layout (bytes):
// [0, 8976)      Ahi 33x136 bf16   } union with: zn fp32 33x132 = [0,17424)
// [8976, 17952)  Alo 33x136 bf16   }            uu 128 f32 = [17408,17920)
//                                               (overlaps only zn row-32 pad)
// [17952, 19232) pp  8x40 f32
#define SMEM_BYTES 19232
#define ALO_OFF_SH 4488
#define UU_OFF_F 4352
#define PP_OFF_F 4488

typedef __attribute__((ext_vector_type(8))) short bf16x8;
typedef __attribute__((ext_vector_type(4))) float f32x4;
typedef __attribute__((ext_vector_type(4))) float float4v;
typedef __attribute__((ext_vector_type(2))) unsigned int uint2v;

__device__ __forceinline__ float bf16bits_to_f32(unsigned short u) {
  return __uint_as_float(((unsigned int)u) << 16);
}
__device__ __forceinline__ void split_bf16(float x, unsigned short& hi, unsigned short& lo) {
  unsigned int xb = __float_as_uint(x);
  hi = (unsigned short)(xb >> 16);
  float hif = __uint_as_float(xb & 0xFFFF0000u);
  float lof = x - hif;  // exact
  lo = (unsigned short)(__float_as_uint(lof) >> 16);
}

// Truncation split of 4 floats into packed hi/lo bf16 pairs via v_perm_b32.
__device__ __forceinline__ void split4_store(float4v v, unsigned short* hp,
                                             unsigned short* lp) {
  unsigned int a = __float_as_uint(v[0]);
  unsigned int b = __float_as_uint(v[1]);
  unsigned int c = __float_as_uint(v[2]);
  unsigned int d = __float_as_uint(v[3]);
  unsigned int h01 = __builtin_amdgcn_perm(b, a, 0x07060302u);
  unsigned int h23 = __builtin_amdgcn_perm(d, c, 0x07060302u);
  unsigned int la = __float_as_uint(v[0] - __uint_as_float(a & 0xFFFF0000u));
  unsigned int lb = __float_as_uint(v[1] - __uint_as_float(b & 0xFFFF0000u));
  unsigned int lc = __float_as_uint(v[2] - __uint_as_float(c & 0xFFFF0000u));
  unsigned int ld = __float_as_uint(v[3] - __uint_as_float(d & 0xFFFF0000u));
  unsigned int l01 = __builtin_amdgcn_perm(lb, la, 0x07060302u);
  unsigned int l23 = __builtin_amdgcn_perm(ld, lc, 0x07060302u);
  *(uint2v*)hp = (uint2v){h01, h23};
  *(uint2v*)lp = (uint2v){l01, l23};
}

// Sum over the 16-lane ml group (capsule columns).
__device__ __forceinline__ float qreduce(float x) {
  x += __shfl_xor(x, 1);
  x += __shfl_xor(x, 2);
  x += __shfl_xor(x, 4);
  x += __shfl_xor(x, 8);
  return x;
}

// W (k-major 128x128) -> MFMA-B fragment-major hi/lo bf16. Self-detects dtype
// (ballot on wave 0); block 0 publishes flag for the routing kernels.
__global__ __launch_bounds__(256) void swizzle_w_kernel(
    const void* __restrict__ w1, int* __restrict__ flag,
    unsigned short* __restrict__ whi, unsigned short* __restrict__ wlo) {
  __shared__ int sflag;
  int t = threadIdx.x;
  if (t < 64) {
    float v = bf16bits_to_f32(((const unsigned short*)w1)[2 * t]);
    int hit = !(fabsf(v) < 1e4f);
    unsigned long long m = __ballot(hit);
    if (t == 0) sflag = (m != 0ull) ? 1 : 0;
  }
  __syncthreads();
  const int isf = sflag;
  if (blockIdx.x == 0 && t == 0) *flag = isf;

  int idx = blockIdx.x * 256 + t;
  int k = idx >> 7, n = idx & 127;
  int kt = k >> 5, q = (k >> 3) & 3, j = k & 7;
  int nt = n >> 4, nl = n & 15;
  int lane = q * 16 + nl;
  int dst = ((kt * 8 + nt) * 64 + lane) * 8 + j;
  unsigned short hb, lb;
  if (isf) {
    split_bf16(((const float*)w1)[idx], hb, lb);
  } else {
    hb = ((const unsigned short*)w1)[idx];
    lb = 0;
  }
  whi[dst] = hb;
  wlo[dst] = lb;
}

// Fused epilogue: bias+relu -> per-row L2-normalize (ml-lane reduce) ->
// write normalized zn; iter-0 routing (uniform p=1/8) entirely in registers
// -> write uu. Caller provides acc with rows mt*16+q*4+r; acc[2] is the
// row-32 broadcast tile (identical value in every lane's row slot).
__device__ __forceinline__ void epilogue_norm_iter0(
    f32x4 acc[3][2], float bias0, float bias1, float* zn, float* uu) {
  const int tid = threadIdx.x;
  const int lane = tid & 63;
  const int wv = tid >> 6;
  const int q = lane >> 4;
  const int ml = lane & 15;
  const int nt0 = wv, nt1 = wv + 4;

#pragma unroll
  for (int jn = 0; jn < 2; ++jn) {
    const int nt = jn ? nt1 : nt0;
    const int col = nt * 16 + ml;
    const float bias = jn ? bias1 : bias0;

    // Self row 32: same value in all lanes of this thread's col (broadcast A).
    float vs = fmaxf(acc[2][jn][0] + bias, 0.f);
    float sss = qreduce(vs * vs);
    float selfn = vs * (1.f / fmaxf(sqrtf(sss), 1e-12f));
    if (q == 0) zn[32 * ZS + col] = selfn;

    // Neighbor rows: mt0 -> rows q*4+r, mt1 -> rows 16+q*4+r.
    float rowsum = 0.f;  // sum of this col's normalized values over my 8 rows
#pragma unroll
    for (int r = 0; r < 4; ++r) {
      float v0 = fmaxf(acc[0][jn][r] + bias, 0.f);
      float ss0 = qreduce(v0 * v0);
      float z0 = v0 * (1.f / fmaxf(sqrtf(ss0), 1e-12f));
      zn[(q * 4 + r) * ZS + col] = z0;
      rowsum += z0;
      float v1 = fmaxf(acc[1][jn][r] + bias, 0.f);
      float ss1 = qreduce(v1 * v1);
      float z1 = v1 * (1.f / fmaxf(sqrtf(ss1), 1e-12f));
      zn[(16 + q * 4 + r) * ZS + col] = z1;
      rowsum += z1;
    }
    // iter 0: sum over all 32 rows (combine the 4 q-groups), uniform p=1/8.
    rowsum += __shfl_xor(rowsum, 16);
    rowsum += __shfl_xor(rowsum, 32);
    float u_raw = 0.125f * rowsum + selfn;
    float ssu = qreduce(u_raw * u_raw);      // capsule sum over 16 cols
    float un = u_raw * (1.f / fmaxf(sqrtf(ssu), 1e-12f));
    if (q == 0) uu[col] = un;
  }
}

// Routing iterations 1,2 (pass1 softmax + pass2 weighted sum) + output.
// Caller must have normalized zn + uu written and a barrier executed.
template <bool OUTF32>
__device__ __forceinline__ void routing_iters(unsigned char* smem, void* out,
                                              size_t bs) {
  float* zn = (float*)smem;
  float* uu = (float*)smem + UU_OFF_F;
  float* pp = (float*)smem + PP_OFF_F;
  const int tid = threadIdx.x;
  const int lane = tid & 63;
  const int wv = tid >> 6;

  const int k2 = tid >> 5, half = (tid >> 4) & 1, c2 = tid & 15;
  const float selfz = zn[32 * ZS + k2 * 16 + c2];  // invariant
  const int k1 = (lane >> 3) & 7;
  const int n1 = (lane & 7) | (wv << 3);

  for (int it = 1; it < 3; ++it) {
    // pass1: logits per (n,k) = dot(u, zn_norm); softmax over k; pp = prob.
    {
      const float4v* up = (const float4v*)&uu[k1 * 16];
      float4v u0 = up[0], u1 = up[1], u2 = up[2], u3 = up[3];
      const float4v* zp = (const float4v*)&zn[n1 * ZS + k1 * 16];
      float4v z0 = zp[0], z1 = zp[1], z2 = zp[2], z3 = zp[3];
      float logit = u0[0]*z0[0]+u0[1]*z0[1]+u0[2]*z0[2]+u0[3]*z0[3]
                  + u1[0]*z1[0]+u1[1]*z1[1]+u1[2]*z1[2]+u1[3]*z1[3]
                  + u2[0]*z2[0]+u2[1]*z2[1]+u2[2]*z2[2]+u2[3]*z2[3]
                  + u3[0]*z3[0]+u3[1]*z3[1]+u3[2]*z3[2]+u3[3]*z3[3];
      float m = logit;  // TAU = 1
      m = fmaxf(m, __shfl_xor(m, 8));
      m = fmaxf(m, __shfl_xor(m, 16));
      m = fmaxf(m, __shfl_xor(m, 32));
      float e = __expf(logit - m);
      float s = e;
      s += __shfl_xor(s, 8);
      s += __shfl_xor(s, 16);
      s += __shfl_xor(s, 32);
      pp[k1 * PPS + n1] = e / s;
      __syncthreads();
    }
    // pass2: (k2,c2) duplicated over half; each half sums 16 n's.
    const float4v* pb = (const float4v*)&pp[k2 * PPS + half * 16];
    float4v p0 = pb[0], p1 = pb[1], p2 = pb[2], p3 = pb[3];
    float s = 0.f;
#pragma unroll
    for (int n0 = 0; n0 < 4; ++n0)
      s += p0[n0] * zn[(half * 16 + n0) * ZS + k2 * 16 + c2];
#pragma unroll
    for (int n0 = 0; n0 < 4; ++n0)
      s += p1[n0] * zn[(half * 16 + 4 + n0) * ZS + k2 * 16 + c2];
#pragma unroll
    for (int n0 = 0; n0 < 4; ++n0)
      s += p2[n0] * zn[(half * 16 + 8 + n0) * ZS + k2 * 16 + c2];
#pragma unroll
    for (int n0 = 0; n0 < 4; ++n0)
      s += p3[n0] * zn[(half * 16 + 12 + n0) * ZS + k2 * 16 + c2];
    s += __shfl_xor(s, 16);     // combine halves
    s += selfz;                 // self capsule (normalized)
    if (it < 2) {
      float ss = s * s;
      ss += __shfl_xor(ss, 1);
      ss += __shfl_xor(ss, 2);
      ss += __shfl_xor(ss, 4);
      ss += __shfl_xor(ss, 8);
      s *= 1.f / fmaxf(sqrtf(ss), 1e-12f);
      if (half == 0) uu[k2 * 16 + c2] = s;
      __syncthreads();
    } else if (half == 0) {
      float r = (s < 0.f) ? 0.f : s;
      const size_t oidx = bs * DD + k2 * 16 + c2;
      if (OUTF32) {
        ((float*)out)[oidx] = r;
      } else {
        unsigned int xb = __float_as_uint(r);
        unsigned int l = (xb >> 16) & 1u;
        ((unsigned short*)out)[oidx] = (unsigned short)((xb + 0x7fffu + l) >> 16);
      }
    }
  }
}

// ---------------- HOT kernel: fp32 inputs (guard: flag!=0) ----------------
// Split-bf16 GEMM, low-pressure schedule: B-frags per kt (short liveness),
// A-pair per mt. Per-acc term order per kt: hh, hl, lh.
__global__ __launch_bounds__(256, 8) void routing_f32_kernel(
    const void* __restrict__ selfv,
    const void* __restrict__ neighv,
    const unsigned short* __restrict__ whi,
    const unsigned short* __restrict__ wlo,
    const void* __restrict__ b1,
    void* __restrict__ out,
    const int* __restrict__ flag) {
  if (*flag == 0) return;  // bf16 inputs -> handled by routing_bf16_kernel
  __shared__ __align__(16) unsigned char smem[SMEM_BYTES];
  unsigned short* Ahi = (unsigned short*)smem;
  unsigned short* Alo = Ahi + ALO_OFF_SH;
  float* zn = (float*)smem;
  float* uu = (float*)smem + UU_OFF_F;

  const int tid = threadIdx.x;
  const int lane = tid & 63;
  const int wv = tid >> 6;
  const int q = lane >> 4;
  const int ml = lane & 15;
  const size_t bs = blockIdx.x;
  const int nt0 = wv, nt1 = wv + 4;

  const float* nf = (const float*)neighv + bs * (size_t)(NB * DD);
  const float* sf = (const float*)selfv + bs * (size_t)DD;
#pragma unroll
  for (int i = 0; i < 4; ++i) {
    int f = tid + (i << 8);  // float4 index 0..1023
    int r = f >> 5, c4 = f & 31;
    float4v v = ((const float4v*)nf)[f];
    split4_store(v, Ahi + r * AST + c4 * 4, Alo + r * AST + c4 * 4);
  }
  if (tid < 32) {
    float4v v = ((const float4v*)sf)[tid];
    split4_store(v, Ahi + 32 * AST + tid * 4, Alo + 32 * AST + tid * 4);
  }
  const float bias0 = ((const float*)b1)[nt0 * 16 + ml];
  const float bias1 = ((const float*)b1)[nt1 * 16 + ml];
  __syncthreads();

  f32x4 acc[3][2];
#pragma unroll
  for (int mt = 0; mt < 3; ++mt)
#pragma unroll
    for (int jn = 0; jn < 2; ++jn) acc[mt][jn] = (f32x4){0.f, 0.f, 0.f, 0.f};

  __builtin_amdgcn_s_setprio(1);
#pragma unroll
  for (int kt = 0; kt < 4; ++kt) {
    const size_t bo0 = ((size_t)(kt * 8 + nt0) * 64 + lane) * 8;
    const size_t bo1 = ((size_t)(kt * 8 + nt1) * 64 + lane) * 8;
    bf16x8 b0h = *(const bf16x8*)(whi + bo0);
    bf16x8 b0l = *(const bf16x8*)(wlo + bo0);
    bf16x8 b1h = *(const bf16x8*)(whi + bo1);
    bf16x8 b1l = *(const bf16x8*)(wlo + bo1);
    const int fo = kt * 32 + q * 8;
#pragma unroll
    for (int mt = 0; mt < 3; ++mt) {
      const int row = (mt == 2) ? 32 : mt * 16 + ml;  // mt=2: broadcast row
      bf16x8 ah = *(const bf16x8*)(Ahi + row * AST + fo);
      bf16x8 al = *(const bf16x8*)(Alo + row * AST + fo);
      acc[mt][0] = __builtin_amdgcn_mfma_f32_16x16x32_bf16(ah, b0h, acc[mt][0], 0, 0, 0);
      acc[mt][1] = __builtin_amdgcn_mfma_f32_16x16x32_bf16(ah, b1h, acc[mt][1], 0, 0, 0);
      acc[mt][0] = __builtin_amdgcn_mfma_f32_16x16x32_bf16(ah, b0l, acc[mt][0], 0, 0, 0);
      acc[mt][1] = __builtin_amdgcn_mfma_f32_16x16x32_bf16(ah, b1l, acc[mt][1], 0, 0, 0);
      acc[mt][0] = __builtin_amdgcn_mfma_f32_16x16x32_bf16(al, b0h, acc[mt][0], 0, 0, 0);
      acc[mt][1] = __builtin_amdgcn_mfma_f32_16x16x32_bf16(al, b1h, acc[mt][1], 0, 0, 0);
    }
  }
  __builtin_amdgcn_s_setprio(0);
  __syncthreads();  // all waves done reading Ahi/Alo before zn overwrites them

  epilogue_norm_iter0(acc, bias0, bias1, zn, uu);
  __syncthreads();

  routing_iters<true>(smem, out, bs);
}

// ---------------- bf16-input kernel (guard: flag==0) ----------------
__global__ __launch_bounds__(256, 8) void routing_bf16_kernel(
    const void* __restrict__ selfv,
    const void* __restrict__ neighv,
    const unsigned short* __restrict__ whi,
    const void* __restrict__ b1,
    void* __restrict__ out,
    const int* __restrict__ flag) {
  if (*flag != 0) return;  // fp32 inputs -> handled by routing_f32_kernel
  __shared__ __align__(16) unsigned char smem[SMEM_BYTES];
  unsigned short* Ahi = (unsigned short*)smem;
  float* zn = (float*)smem;
  float* uu = (float*)smem + UU_OFF_F;

  const int tid = threadIdx.x;
  const int lane = tid & 63;
  const int wv = tid >> 6;
  const int q = lane >> 4;
  const int ml = lane & 15;
  const size_t bs = blockIdx.x;
  const int nt0 = wv, nt1 = wv + 4;

  const unsigned short* nbf = (const unsigned short*)neighv + bs * (size_t)(NB * DD);
  const unsigned short* sbf = (const unsigned short*)selfv + bs * (size_t)DD;
#pragma unroll
  for (int i = 0; i < 2; ++i) {
    int s = tid + (i << 8);  // 16B chunk 0..511
    int r = s >> 4, c8 = s & 15;
    bf16x8 v = *(const bf16x8*)(nbf + r * DD + c8 * 8);
    *(bf16x8*)(Ahi + r * AST + c8 * 8) = v;
  }
  if (tid < 16) {
    bf16x8 v = *(const bf16x8*)(sbf + tid * 8);
    *(bf16x8*)(Ahi + 32 * AST + tid * 8) = v;
  }
  const float bias0 = bf16bits_to_f32(((const unsigned short*)b1)[nt0 * 16 + ml]);
  const float bias1 = bf16bits_to_f32(((const unsigned short*)b1)[nt1 * 16 + ml]);
  __syncthreads();

  f32x4 acc[3][2];
#pragma unroll
  for (int mt = 0; mt < 3; ++mt)
#pragma unroll
    for (int jn = 0; jn < 2; ++jn) acc[mt][jn] = (f32x4){0.f, 0.f, 0.f, 0.f};

  __builtin_amdgcn_s_setprio(1);
#pragma unroll
  for (int kt = 0; kt < 4; ++kt) {
    bf16x8 b0h = *(const bf16x8*)(whi + ((size_t)(kt * 8 + nt0) * 64 + lane) * 8);
    bf16x8 b1h = *(const bf16x8*)(whi + ((size_t)(kt * 8 + nt1) * 64 + lane) * 8);
    const int fo = kt * 32 + q * 8;
#pragma unroll
    for (int mt = 0; mt < 3; ++mt) {
      const int row = (mt == 2) ? 32 : mt * 16 + ml;  // mt=2: broadcast row
      bf16x8 ah = *(const bf16x8*)(Ahi + row * AST + fo);
      acc[mt][0] = __builtin_amdgcn_mfma_f32_16x16x32_bf16(ah, b0h, acc[mt][0], 0, 0, 0);
      acc[mt][1] = __builtin_amdgcn_mfma_f32_16x16x32_bf16(ah, b1h, acc[mt][1], 0, 0, 0);
    }
  }
  __builtin_amdgcn_s_setprio(0);
  __syncthreads();  // all waves done reading Ahi before zn overwrites it

  epilogue_norm_iter0(acc, bias0, bias1, zn, uu);
  __syncthreads();

  routing_iters<false>(smem, out, bs);
}

extern "C" void kernel_launch(void* const* d_in, const int* in_sizes, int n_in,
                              void* d_out, int out_size, void* d_ws, size_t ws_size,
                              hipStream_t stream) {
  (void)in_sizes; (void)n_in; (void)out_size; (void)ws_size;
  const void* selfv = d_in[0];
  const void* neighv = d_in[1];
  const void* w1 = d_in[2];
  const void* b1 = d_in[3];
  int* flag = (int*)d_ws;
  unsigned short* whi = (unsigned short*)((char*)d_ws + 64);
  unsigned short* wlo = (unsigned short*)((char*)d_ws + 64 + 32768);

  swizzle_w_kernel<<<64, 256, 0, stream>>>(w1, flag, whi, wlo);
  routing_f32_kernel<<<8192, 256, 0, stream>>>(selfv, neighv, whi, wlo, b1,
                                               d_out, flag);
  routing_bf16_kernel<<<8192, 256, 0, stream>>>(selfv, neighv, whi, b1,
                                                d_out, flag);
}

// Round 10
// 224.628 us; speedup vs baseline: 1.0894x; 1.0894x over previous
//
#include <hip/hip_runtime.h>
#include <hip/hip_bf16.h>

// RoutingLayer: B=128,S=64,N=32, D=128, K=8 capsules x C=16, 3 routing iters.
// fp32 OR bf16 inputs, MFMA GEMM, fused routing.
// R15 (revert R14 fusion; host-side dtype dispatch):
//  - R14 regression attributed: in-register epilogue = ~84 serial shfl_xor
//    (DS-pipe) per thread, VALUBusy 40->68%, +1-reg spill. Reverted to R13's
//    LDS phase structure (best verified: 78.6us routing).
//  - Dead-launch elimination: in_sizes bytes identify dtype on the HOST
//    (selfv 4MB fp32 vs 2MB bf16). When unambiguous, launch ONLY the right
//    kernel with certain=1 (no flag read, no ballot in swizzle). Ambiguous
//    -> fall back to flag-guarded dual launch (strictly safe).
//  - s_setprio(1) kept around MFMA cluster only (independent-block regime).
// Carried: two-kernel dtype split (clean register allocation; R8-R10 proved
// shared-kernel arms spill), R12 low-pressure GEMM schedule, 8 blocks/CU,
// v_perm splits, conflict-free lane maps, PPS=40 broadcast pass2, R13
// in-place zn normalization (no nrm array).

#define NB 32
#define DD 128
#define ZS 132   // zn row stride (floats)
#define PPS 40   // pp row stride (floats) — 160B, 16B-aligned
#define AST 136  // staged A row stride (bf16 units) = 272 B, 16B-aligned

// LDS layout (bytes):
// [0, 8976)      Ahi 33x136 bf16   } union with: zn fp32 33x132 = [0,17424)
// [8976, 17952)  Alo 33x136 bf16   }            uu 128 f32 = [17408,17920)
//                                               (overlaps only zn row-32 pad)
// [17952, 19232) pp  8x40 f32
#define SMEM_BYTES 19232
#define ALO_OFF_SH 4488
#define UU_OFF_F 4352
#define PP_OFF_F 4488

typedef __attribute__((ext_vector_type(8))) short bf16x8;
typedef __attribute__((ext_vector_type(4))) float f32x4;
typedef __attribute__((ext_vector_type(4))) float float4v;
typedef __attribute__((ext_vector_type(2))) unsigned int uint2v;

__device__ __forceinline__ float bf16bits_to_f32(unsigned short u) {
  return __uint_as_float(((unsigned int)u) << 16);
}
__device__ __forceinline__ void split_bf16(float x, unsigned short& hi, unsigned short& lo) {
  unsigned int xb = __float_as_uint(x);
  hi = (unsigned short)(xb >> 16);
  float hif = __uint_as_float(xb & 0xFFFF0000u);
  float lof = x - hif;  // exact
  lo = (unsigned short)(__float_as_uint(lof) >> 16);
}

// Truncation split of 4 floats into packed hi/lo bf16 pairs via v_perm_b32.
__device__ __forceinline__ void split4_store(float4v v, unsigned short* hp,
                                             unsigned short* lp) {
  unsigned int a = __float_as_uint(v[0]);
  unsigned int b = __float_as_uint(v[1]);
  unsigned int c = __float_as_uint(v[2]);
  unsigned int d = __float_as_uint(v[3]);
  unsigned int h01 = __builtin_amdgcn_perm(b, a, 0x07060302u);
  unsigned int h23 = __builtin_amdgcn_perm(d, c, 0x07060302u);
  unsigned int la = __float_as_uint(v[0] - __uint_as_float(a & 0xFFFF0000u));
  unsigned int lb = __float_as_uint(v[1] - __uint_as_float(b & 0xFFFF0000u));
  unsigned int lc = __float_as_uint(v[2] - __uint_as_float(c & 0xFFFF0000u));
  unsigned int ld = __float_as_uint(v[3] - __uint_as_float(d & 0xFFFF0000u));
  unsigned int l01 = __builtin_amdgcn_perm(lb, la, 0x07060302u);
  unsigned int l23 = __builtin_amdgcn_perm(ld, lc, 0x07060302u);
  *(uint2v*)hp = (uint2v){h01, h23};
  *(uint2v*)lp = (uint2v){l01, l23};
}

// W (k-major 128x128) -> MFMA-B fragment-major hi/lo bf16. hmode: 1=f32,
// 0=bf16 (host-certain), -1=detect via ballot; block 0 publishes flag.
__global__ __launch_bounds__(256) void swizzle_w_kernel(
    const void* __restrict__ w1, int* __restrict__ flag,
    unsigned short* __restrict__ whi, unsigned short* __restrict__ wlo,
    int hmode) {
  __shared__ int sflag;
  int t = threadIdx.x;
  int isf;
  if (hmode >= 0) {
    isf = hmode;
  } else {
    if (t < 64) {
      float v = bf16bits_to_f32(((const unsigned short*)w1)[2 * t]);
      int hit = !(fabsf(v) < 1e4f);
      unsigned long long m = __ballot(hit);
      if (t == 0) sflag = (m != 0ull) ? 1 : 0;
    }
    __syncthreads();
    isf = sflag;
  }
  if (blockIdx.x == 0 && t == 0) *flag = isf;

  int idx = blockIdx.x * 256 + t;
  int k = idx >> 7, n = idx & 127;
  int kt = k >> 5, q = (k >> 3) & 3, j = k & 7;
  int nt = n >> 4, nl = n & 15;
  int lane = q * 16 + nl;
  int dst = ((kt * 8 + nt) * 64 + lane) * 8 + j;
  unsigned short hb, lb;
  if (isf) {
    split_bf16(((const float*)w1)[idx], hb, lb);
  } else {
    hb = ((const unsigned short*)w1)[idx];
    lb = 0;
  }
  whi[dst] = hb;
  wlo[dst] = lb;
}

// Shared post-GEMM tail: in-place zn normalize + 3 routing iters + store.
// Caller must have raw zn fully written and a barrier executed before calling.
template <bool OUTF32>
__device__ __forceinline__ void routing_tail(unsigned char* smem, void* out,
                                             size_t bs) {
  float* zn = (float*)smem;
  float* uu = (float*)smem + UU_OFF_F;
  float* pp = (float*)smem + PP_OFF_F;
  const int tid = threadIdx.x;
  const int lane = tid & 63;
  const int wv = tid >> 6;

  // Normalize zn in place per (row,k) capsule slice. Row fast-varying lane
  // map -> conflict-free b128 reads/writes. One thread owns one slice.
  {
    const int rowr = (tid & 7) | ((tid >> 6) << 3);  // 0..31
    const int kr = (tid >> 3) & 7;                   // 0..7
    float4v* zp = (float4v*)&zn[rowr * ZS + kr * 16];
    float4v a = zp[0], b = zp[1], c = zp[2], d = zp[3];
    float ss = a[0]*a[0]+a[1]*a[1]+a[2]*a[2]+a[3]*a[3]
             + b[0]*b[0]+b[1]*b[1]+b[2]*b[2]+b[3]*b[3]
             + c[0]*c[0]+c[1]*c[1]+c[2]*c[2]+c[3]*c[3]
             + d[0]*d[0]+d[1]*d[1]+d[2]*d[2]+d[3]*d[3];
    float nv = 1.f / fmaxf(sqrtf(ss), 1e-12f);
    zp[0] = a * nv; zp[1] = b * nv; zp[2] = c * nv; zp[3] = d * nv;
  }
  if (tid < 8) {  // self row 32, k = tid
    float4v* zp = (float4v*)&zn[32 * ZS + tid * 16];
    float4v a = zp[0], b = zp[1], c = zp[2], d = zp[3];
    float ss = a[0]*a[0]+a[1]*a[1]+a[2]*a[2]+a[3]*a[3]
             + b[0]*b[0]+b[1]*b[1]+b[2]*b[2]+b[3]*b[3]
             + c[0]*c[0]+c[1]*c[1]+c[2]*c[2]+c[3]*c[3]
             + d[0]*d[0]+d[1]*d[1]+d[2]*d[2]+d[3]*d[3];
    float nv = 1.f / fmaxf(sqrtf(ss), 1e-12f);
    zp[0] = a * nv; zp[1] = b * nv; zp[2] = c * nv; zp[3] = d * nv;
  }
  __syncthreads();

  const int k2 = tid >> 5, half = (tid >> 4) & 1, c2 = tid & 15;
  const float selfz = zn[32 * ZS + k2 * 16 + c2];  // invariant: row 32 fixed
  const int k1 = (lane >> 3) & 7;
  const int n1 = (lane & 7) | (wv << 3);

  // ---- iter 0: uniform p = 1/8, no pp involved ----
  {
    float s = 0.f;
#pragma unroll
    for (int n0 = 0; n0 < 16; ++n0)
      s += zn[(half * 16 + n0) * ZS + k2 * 16 + c2];
    s += __shfl_xor(s, 16);        // combine halves
    s = 0.125f * s + selfz;        // uniform prob + self capsule
    float ss = s * s;
    ss += __shfl_xor(ss, 1);
    ss += __shfl_xor(ss, 2);
    ss += __shfl_xor(ss, 4);
    ss += __shfl_xor(ss, 8);
    s *= 1.f / fmaxf(sqrtf(ss), 1e-12f);
    if (half == 0) uu[k2 * 16 + c2] = s;
    __syncthreads();
  }

  // ---- iters 1,2 ----
  for (int it = 1; it < 3; ++it) {
    // pass1: logits per (n,k) = dot(u, zn_norm); softmax over k; pp = prob.
    {
      const float4v* up = (const float4v*)&uu[k1 * 16];
      float4v u0 = up[0], u1 = up[1], u2 = up[2], u3 = up[3];
      const float4v* zp = (const float4v*)&zn[n1 * ZS + k1 * 16];
      float4v z0 = zp[0], z1 = zp[1], z2 = zp[2], z3 = zp[3];
      float logit = u0[0]*z0[0]+u0[1]*z0[1]+u0[2]*z0[2]+u0[3]*z0[3]
                  + u1[0]*z1[0]+u1[1]*z1[1]+u1[2]*z1[2]+u1[3]*z1[3]
                  + u2[0]*z2[0]+u2[1]*z2[1]+u2[2]*z2[2]+u2[3]*z2[3]
                  + u3[0]*z3[0]+u3[1]*z3[1]+u3[2]*z3[2]+u3[3]*z3[3];
      float m = logit;  // TAU = 1
      m = fmaxf(m, __shfl_xor(m, 8));
      m = fmaxf(m, __shfl_xor(m, 16));
      m = fmaxf(m, __shfl_xor(m, 32));
      float e = __expf(logit - m);
      float s = e;
      s += __shfl_xor(s, 8);
      s += __shfl_xor(s, 16);
      s += __shfl_xor(s, 32);
      pp[k1 * PPS + n1] = e / s;
      __syncthreads();
    }
    // pass2: (k2,c2) duplicated over half; each half sums 16 n's.
    const float4v* pb = (const float4v*)&pp[k2 * PPS + half * 16];
    float4v p0 = pb[0], p1 = pb[1], p2 = pb[2], p3 = pb[3];
    float s = 0.f;
#pragma unroll
    for (int n0 = 0; n0 < 4; ++n0)
      s += p0[n0] * zn[(half * 16 + n0) * ZS + k2 * 16 + c2];
#pragma unroll
    for (int n0 = 0; n0 < 4; ++n0)
      s += p1[n0] * zn[(half * 16 + 4 + n0) * ZS + k2 * 16 + c2];
#pragma unroll
    for (int n0 = 0; n0 < 4; ++n0)
      s += p2[n0] * zn[(half * 16 + 8 + n0) * ZS + k2 * 16 + c2];
#pragma unroll
    for (int n0 = 0; n0 < 4; ++n0)
      s += p3[n0] * zn[(half * 16 + 12 + n0) * ZS + k2 * 16 + c2];
    s += __shfl_xor(s, 16);     // combine halves
    s += selfz;                 // self capsule (already normalized)
    if (it < 2) {
      float ss = s * s;
      ss += __shfl_xor(ss, 1);
      ss += __shfl_xor(ss, 2);
      ss += __shfl_xor(ss, 4);
      ss += __shfl_xor(ss, 8);
      s *= 1.f / fmaxf(sqrtf(ss), 1e-12f);
      if (half == 0) uu[k2 * 16 + c2] = s;
      __syncthreads();
    } else if (half == 0) {
      float r = (s < 0.f) ? 0.f : s;
      const size_t oidx = bs * DD + k2 * 16 + c2;
      if (OUTF32) {
        ((float*)out)[oidx] = r;
      } else {
        unsigned int xb = __float_as_uint(r);
        unsigned int l = (xb >> 16) & 1u;
        ((unsigned short*)out)[oidx] = (unsigned short)((xb + 0x7fffu + l) >> 16);
      }
    }
  }
}

// ---------------- fp32-input kernel ----------------
// Split-bf16 GEMM, low-pressure schedule: B-frags per kt (short liveness),
// A-pair per mt. Per-acc term order per kt: hh, hl, lh.
__global__ __launch_bounds__(256, 8) void routing_f32_kernel(
    const void* __restrict__ selfv,
    const void* __restrict__ neighv,
    const unsigned short* __restrict__ whi,
    const unsigned short* __restrict__ wlo,
    const void* __restrict__ b1,
    void* __restrict__ out,
    const int* __restrict__ flag, int certain) {
  if (!certain && *flag == 0) return;  // bf16 inputs -> other kernel
  __shared__ __align__(16) unsigned char smem[SMEM_BYTES];
  unsigned short* Ahi = (unsigned short*)smem;
  unsigned short* Alo = Ahi + ALO_OFF_SH;
  float* zn = (float*)smem;

  const int tid = threadIdx.x;
  const int lane = tid & 63;
  const int wv = tid >> 6;
  const int q = lane >> 4;
  const int ml = lane & 15;
  const size_t bs = blockIdx.x;
  const int nt0 = wv, nt1 = wv + 4;

  const float* nf = (const float*)neighv + bs * (size_t)(NB * DD);
  const float* sf = (const float*)selfv + bs * (size_t)DD;
#pragma unroll
  for (int i = 0; i < 4; ++i) {
    int f = tid + (i << 8);  // float4 index 0..1023
    int r = f >> 5, c4 = f & 31;
    float4v v = ((const float4v*)nf)[f];
    split4_store(v, Ahi + r * AST + c4 * 4, Alo + r * AST + c4 * 4);
  }
  if (tid < 32) {
    float4v v = ((const float4v*)sf)[tid];
    split4_store(v, Ahi + 32 * AST + tid * 4, Alo + 32 * AST + tid * 4);
  }
  const float bias0 = ((const float*)b1)[nt0 * 16 + ml];
  const float bias1 = ((const float*)b1)[nt1 * 16 + ml];
  __syncthreads();

  f32x4 acc[3][2];
#pragma unroll
  for (int mt = 0; mt < 3; ++mt)
#pragma unroll
    for (int jn = 0; jn < 2; ++jn) acc[mt][jn] = (f32x4){0.f, 0.f, 0.f, 0.f};

  __builtin_amdgcn_s_setprio(1);
#pragma unroll
  for (int kt = 0; kt < 4; ++kt) {
    const size_t bo0 = ((size_t)(kt * 8 + nt0) * 64 + lane) * 8;
    const size_t bo1 = ((size_t)(kt * 8 + nt1) * 64 + lane) * 8;
    bf16x8 b0h = *(const bf16x8*)(whi + bo0);
    bf16x8 b0l = *(const bf16x8*)(wlo + bo0);
    bf16x8 b1h = *(const bf16x8*)(whi + bo1);
    bf16x8 b1l = *(const bf16x8*)(wlo + bo1);
    const int fo = kt * 32 + q * 8;
#pragma unroll
    for (int mt = 0; mt < 3; ++mt) {
      const int row = (mt == 2) ? 32 : mt * 16 + ml;  // mt=2: broadcast row
      bf16x8 ah = *(const bf16x8*)(Ahi + row * AST + fo);
      bf16x8 al = *(const bf16x8*)(Alo + row * AST + fo);
      acc[mt][0] = __builtin_amdgcn_mfma_f32_16x16x32_bf16(ah, b0h, acc[mt][0], 0, 0, 0);
      acc[mt][1] = __builtin_amdgcn_mfma_f32_16x16x32_bf16(ah, b1h, acc[mt][1], 0, 0, 0);
      acc[mt][0] = __builtin_amdgcn_mfma_f32_16x16x32_bf16(ah, b0l, acc[mt][0], 0, 0, 0);
      acc[mt][1] = __builtin_amdgcn_mfma_f32_16x16x32_bf16(ah, b1l, acc[mt][1], 0, 0, 0);
      acc[mt][0] = __builtin_amdgcn_mfma_f32_16x16x32_bf16(al, b0h, acc[mt][0], 0, 0, 0);
      acc[mt][1] = __builtin_amdgcn_mfma_f32_16x16x32_bf16(al, b1h, acc[mt][1], 0, 0, 0);
    }
  }
  __builtin_amdgcn_s_setprio(0);
  __syncthreads();  // all waves done reading Ahi/Alo before zn overwrites them

#pragma unroll
  for (int jn = 0; jn < 2; ++jn) {
    const int nt = jn ? nt1 : nt0;
    const int col = nt * 16 + ml;
    const float bias = jn ? bias1 : bias0;
#pragma unroll
    for (int mt = 0; mt < 3; ++mt) {
#pragma unroll
      for (int r = 0; r < 4; ++r) {
        const int row = mt * 16 + q * 4 + r;
        float v = fmaxf(acc[mt][jn][r] + bias, 0.f);
        if (row < 33) zn[row * ZS + col] = v;
      }
    }
  }
  __syncthreads();

  routing_tail<true>(smem, out, bs);
}

// ---------------- bf16-input kernel ----------------
__global__ __launch_bounds__(256, 8) void routing_bf16_kernel(
    const void* __restrict__ selfv,
    const void* __restrict__ neighv,
    const unsigned short* __restrict__ whi,
    const void* __restrict__ b1,
    void* __restrict__ out,
    const int* __restrict__ flag, int certain) {
  if (!certain && *flag != 0) return;  // fp32 inputs -> other kernel
  __shared__ __align__(16) unsigned char smem[SMEM_BYTES];
  unsigned short* Ahi = (unsigned short*)smem;
  float* zn = (float*)smem;  // union: valid after GEMM

  const int tid = threadIdx.x;
  const int lane = tid & 63;
  const int wv = tid >> 6;
  const int q = lane >> 4;
  const int ml = lane & 15;
  const size_t bs = blockIdx.x;
  const int nt0 = wv, nt1 = wv + 4;

  const unsigned short* nbf = (const unsigned short*)neighv + bs * (size_t)(NB * DD);
  const unsigned short* sbf = (const unsigned short*)selfv + bs * (size_t)DD;
#pragma unroll
  for (int i = 0; i < 2; ++i) {
    int s = tid + (i << 8);  // 16B chunk 0..511
    int r = s >> 4, c8 = s & 15;
    bf16x8 v = *(const bf16x8*)(nbf + r * DD + c8 * 8);
    *(bf16x8*)(Ahi + r * AST + c8 * 8) = v;
  }
  if (tid < 16) {
    bf16x8 v = *(const bf16x8*)(sbf + tid * 8);
    *(bf16x8*)(Ahi + 32 * AST + tid * 8) = v;
  }
  const float bias0 = bf16bits_to_f32(((const unsigned short*)b1)[nt0 * 16 + ml]);
  const float bias1 = bf16bits_to_f32(((const unsigned short*)b1)[nt1 * 16 + ml]);
  __syncthreads();

  f32x4 acc[3][2];
#pragma unroll
  for (int mt = 0; mt < 3; ++mt)
#pragma unroll
    for (int jn = 0; jn < 2; ++jn) acc[mt][jn] = (f32x4){0.f, 0.f, 0.f, 0.f};

  __builtin_amdgcn_s_setprio(1);
#pragma unroll
  for (int kt = 0; kt < 4; ++kt) {
    bf16x8 b0h = *(const bf16x8*)(whi + ((size_t)(kt * 8 + nt0) * 64 + lane) * 8);
    bf16x8 b1h = *(const bf16x8*)(whi + ((size_t)(kt * 8 + nt1) * 64 + lane) * 8);
    const int fo = kt * 32 + q * 8;
#pragma unroll
    for (int mt = 0; mt < 3; ++mt) {
      const int row = (mt == 2) ? 32 : mt * 16 + ml;  // mt=2: broadcast row
      bf16x8 ah = *(const bf16x8*)(Ahi + row * AST + fo);
      acc[mt][0] = __builtin_amdgcn_mfma_f32_16x16x32_bf16(ah, b0h, acc[mt][0], 0, 0, 0);
      acc[mt][1] = __builtin_amdgcn_mfma_f32_16x16x32_bf16(ah, b1h, acc[mt][1], 0, 0, 0);
    }
  }
  __builtin_amdgcn_s_setprio(0);
  __syncthreads();  // all waves done reading Ahi before zn overwrites it

  // Epilogue: bias + relu -> RAW zn (fp32) over the staging region.
#pragma unroll
  for (int jn = 0; jn < 2; ++jn) {
    const int nt = jn ? nt1 : nt0;
    const int col = nt * 16 + ml;
    const float bias = jn ? bias1 : bias0;
#pragma unroll
    for (int mt = 0; mt < 3; ++mt) {
#pragma unroll
      for (int r = 0; r < 4; ++r) {
        const int row = mt * 16 + q * 4 + r;
        float v = fmaxf(acc[mt][jn][r] + bias, 0.f);
        if (row < 33) zn[row * ZS + col] = v;
      }
    }
  }
  __syncthreads();

  routing_tail<false>(smem, out, bs);
}

extern "C" void kernel_launch(void* const* d_in, const int* in_sizes, int n_in,
                              void* d_out, int out_size, void* d_ws, size_t ws_size,
                              hipStream_t stream) {
  (void)out_size; (void)ws_size;
  const void* selfv = d_in[0];
  const void* neighv = d_in[1];
  const void* w1 = d_in[2];
  const void* b1 = d_in[3];
  int* flag = (int*)d_ws;
  unsigned short* whi = (unsigned short*)((char*)d_ws + 64);
  unsigned short* wlo = (unsigned short*)((char*)d_ws + 64 + 32768);

  // Host-side dtype detection from input byte sizes (selfv: 128*64*128 el).
  // fp32: 4194304 / 134217728 B; bf16: 2097152 / 67108864 B. If in_sizes
  // carries element counts (ambiguous), fall back to device-side flag guard.
  int hmode = -1;
  if (in_sizes && n_in >= 2) {
    const long long s0 = in_sizes[0], s1 = in_sizes[1];
    if (s0 == 4194304LL && s1 == 134217728LL) hmode = 1;
    else if (s0 == 2097152LL && s1 == 67108864LL) hmode = 0;
  }

  swizzle_w_kernel<<<64, 256, 0, stream>>>(w1, flag, whi, wlo, hmode);
  if (hmode != 0)
    routing_f32_kernel<<<8192, 256, 0, stream>>>(selfv, neighv, whi, wlo, b1,
                                                 d_out, flag, hmode == 1);
  if (hmode != 1)
    routing_bf16_kernel<<<8192, 256, 0, stream>>>(selfv, neighv, whi, b1,
                                                  d_out, flag, hmode == 0);
}